// Round 11
// baseline (48.473 us; speedup 1.0000x reference)
//
#include <hip/hip_runtime.h>
#include <hip/hip_bf16.h>
#include <math.h>

#define D_MODEL 2048
#define N_EXP   64
#define NTOK    16384           // 4 * 4096
#define NBLK    512             // NTOK / 32 tokens per block
#define NSTG    16              // K stages: 2048 / 128

typedef short bf16x8 __attribute__((ext_vector_type(8)));
typedef float f32x16 __attribute__((ext_vector_type(16)));
typedef unsigned int u32;

// out layout (floats)
#define OFF_PROBS 0
#define OFF_IDX   32768
#define OFF_MASK  65536
#define OFF_AUX   1114112
#define OFF_ENT   1114113

#define WF_PS 16384            // bf16x8 units per split-part (128 g * 2 n * 64)

#define MEMFENCE asm volatile("" ::: "memory")
// fence + barrier + fence: s_barrier alone is NOT a compiler memory fence;
// without the trailing fence the compiler may hoist next-stage LDS reads
// above the barrier (r9 failure: cross-wave stage rows read stale).
#define FULLBAR() do { MEMFENCE; __builtin_amdgcn_s_barrier(); MEMFENCE; \
                       __builtin_amdgcn_sched_barrier(0); } while (0)

__device__ __forceinline__ void split3(float xv, u32& h, u32& m, u32& l) {
  u32 xb = __builtin_bit_cast(u32, xv);
  u32 hb = xb & 0xFFFF0000u;
  float tf = xv - __builtin_bit_cast(float, hb);      // exact (Sterbenz)
  u32 tb = __builtin_bit_cast(u32, tf);
  u32 mb = tb & 0xFFFF0000u;
  float t2 = tf - __builtin_bit_cast(float, mb);      // exact; bf16-representable
  u32 lb = __builtin_bit_cast(u32, t2);
  h = hb >> 16; m = mb >> 16; l = lb >> 16;
}

__device__ __forceinline__ bool better(float a, int ia, float b, int ib) {
  return (a > b) || (a == b && ia < ib);
}

// W[64][2048] -> 3 bf16 parts in 32x32x16 B-fragment order. (verified r5-r8)
// r20: also zeroes the finalize ticket each launch (runs before finalize).
__global__ __launch_bounds__(256) void wprep_kernel(
    const float* __restrict__ W, bf16x8* __restrict__ Wf,
    u32* __restrict__ ticket) {
  if (blockIdx.x == 0 && threadIdx.x == 0) ticket[0] = 0u;
  int gid  = blockIdx.x * 256 + threadIdx.x;   // 16384
  int g    = gid >> 7;
  int n    = (gid >> 6) & 1;
  int lane = gid & 63;
  int e    = n * 32 + (lane & 31);
  int k    = g * 16 + ((lane >> 5) << 3);
  const float* wr = W + (size_t)e * D_MODEL + k;
  bf16x8 hv, mv, lv;
#pragma unroll
  for (int j = 0; j < 8; ++j) {
    u32 h, m, l;
    split3(wr[j], h, m, l);
    hv[j] = (short)h; mv[j] = (short)m; lv[j] = (short)l;
  }
  Wf[gid]             = hv;
  Wf[WF_PS + gid]     = mv;
  Wf[2 * WF_PS + gid] = lv;
}

// r20: fused = r17 EXACT (44.4us verified best: stagger st0=b&15 fixed
// channel camping). r19 post-mortem: XCD-corrected stagger (b>>3)&15 was a
// null (44.9 ~ 44.4) -> stagger benefit saturated at either granularity;
// per-XCD window concentration is not the residual limiter. Residual-gap
// audit: DRAM activation rate, L2 BW, VALU/MFMA all well under their
// ceilings -> no remaining theory predicts a large fused win. This round
// attacks dispatch-chain overhead only; fused untouched.
__global__ __launch_bounds__(512, 4) void fused_kernel(
    const float* __restrict__ x, const bf16x8* __restrict__ Wf,
    const float* __restrict__ temp, float* __restrict__ out,
    float* __restrict__ imp_part, float* __restrict__ load_part,
    float* __restrict__ ent_part) {
  __shared__ float lds[16384];   // 64 KB: 4 bufs x 32 rows x 128 floats
  const int tid  = threadIdx.x;
  const int w    = tid >> 6;
  const int lane = tid & 63;
  const int t0   = blockIdx.x * 32;
  const int rl   = lane & 31;
  const int hg   = lane >> 5;
  const int st0  = blockIdx.x & 15;      // K-phase stagger (r17, verified)

  float tv = temp[0];
  tv = fminf(fmaxf(tv, 0.1f), 5.0f);
  const float invT = 1.0f / tv;

  // glds source bases (i=0,1): rows r0=w*4+i*2; lane covers row r0+hg,
  // physical chunk (lane&31) holds logical chunk (lane&31)^row.
  const float* gsrc[2];
#pragma unroll
  for (int i = 0; i < 2; ++i) {
    int r0  = w * 4 + i * 2;
    int row = r0 + hg;
    int sc  = rl ^ (row & 31);
    gsrc[i] = x + (size_t)(t0 + row) * D_MODEL + sc * 4;
  }

  auto stage = [&](int st) {             // st = physical stage index
    const int buf = st & 3;
    const int kst = (st0 + st) & 15;     // logical k-stage
#pragma unroll
    for (int i = 0; i < 2; ++i) {
      int r0 = w * 4 + i * 2;             // wave-uniform dest base
      __builtin_amdgcn_global_load_lds(
          (const __attribute__((address_space(1))) void*)(gsrc[i] + kst * 128),
          (__attribute__((address_space(3))) void*)(lds + buf * 4096 + r0 * 128),
          16, 0, 0);
    }
  };
  auto loadB = [&](int st, bf16x8* bb) { // st = physical stage index
    const int kst = (st0 + st) & 15;
    const bf16x8* wp = Wf + (size_t)(kst * 8 + w) * 128 + lane;
#pragma unroll
    for (int p = 0; p < 3; ++p)
#pragma unroll
      for (int n = 0; n < 2; ++n)
        bb[p * 2 + n] = wp[p * WF_PS + n * 64];
  };

  f32x16 acc0, acc1;
#pragma unroll
  for (int i = 0; i < 16; ++i) { acc0[i] = 0.0f; acc1[i] = 0.0f; }

  bf16x8 b[2][6];
  stage(0); stage(1);            // 4 glds in flight
  loadB(0, b[0]);                // 6 B-loads
  // S0 retired when newer-than-S0 (S1:2 + B0:6 = 8) are the only outstanding
  asm volatile("s_waitcnt vmcnt(8)" ::: "memory");
  FULLBAR();

  const int c0 = w * 4 + hg * 2;         // logical 16B-chunk of this lane

#pragma unroll
  for (int st = 0; st < NSTG; ++st) {
    if (st + 1 < NSTG) loadB(st + 1, b[(st + 1) & 1]);
    if (st + 2 < NSTG) stage(st + 2);

    const float* rb = lds + (st & 3) * 4096 + rl * 128;
    float4 a0 = *(const float4*)(rb + ((c0 ^ rl) << 2));
    float4 a1 = *(const float4*)(rb + (((c0 + 1) ^ rl) << 2));
    float av[8] = {a0.x, a0.y, a0.z, a0.w, a1.x, a1.y, a1.z, a1.w};
    bf16x8 ah, am, al;
#pragma unroll
    for (int j = 0; j < 8; ++j) {
      u32 hh, mm, ll;
      split3(av[j], hh, mm, ll);
      ah[j] = (short)hh; am[j] = (short)mm; al[j] = (short)ll;
    }
    const bf16x8* bb = b[st & 1];
    acc0 = __builtin_amdgcn_mfma_f32_32x32x16_bf16(ah, bb[0], acc0, 0, 0, 0);
    acc1 = __builtin_amdgcn_mfma_f32_32x32x16_bf16(ah, bb[1], acc1, 0, 0, 0);
    acc0 = __builtin_amdgcn_mfma_f32_32x32x16_bf16(ah, bb[2], acc0, 0, 0, 0);
    acc1 = __builtin_amdgcn_mfma_f32_32x32x16_bf16(ah, bb[3], acc1, 0, 0, 0);
    acc0 = __builtin_amdgcn_mfma_f32_32x32x16_bf16(am, bb[0], acc0, 0, 0, 0);
    acc1 = __builtin_amdgcn_mfma_f32_32x32x16_bf16(am, bb[1], acc1, 0, 0, 0);
    acc0 = __builtin_amdgcn_mfma_f32_32x32x16_bf16(am, bb[2], acc0, 0, 0, 0);
    acc1 = __builtin_amdgcn_mfma_f32_32x32x16_bf16(am, bb[3], acc1, 0, 0, 0);
    acc0 = __builtin_amdgcn_mfma_f32_32x32x16_bf16(ah, bb[4], acc0, 0, 0, 0);
    acc1 = __builtin_amdgcn_mfma_f32_32x32x16_bf16(ah, bb[5], acc1, 0, 0, 0);
    acc0 = __builtin_amdgcn_mfma_f32_32x32x16_bf16(al, bb[0], acc0, 0, 0, 0);
    acc1 = __builtin_amdgcn_mfma_f32_32x32x16_bf16(al, bb[1], acc1, 0, 0, 0);

    // end-of-stage: S(st+1) retired iff newest 8 (B(st+1):6 + S(st+2):2)
    // are the only outstanding. Tail st=14: only B15:6 newer -> vmcnt(6).
    if (st < NSTG - 2) {
      asm volatile("s_waitcnt vmcnt(8)" ::: "memory");
      FULLBAR();
    } else if (st == NSTG - 2) {
      asm volatile("s_waitcnt vmcnt(6)" ::: "memory");
      FULLBAR();
    }
  }

  // ---- epilogue: 8-way K reduction in LDS (verified r7/r8) ----
  __syncthreads();
#pragma unroll
  for (int r = 0; r < 16; ++r) {
    int row = (r & 3) + ((r >> 2) << 3) + (hg << 2);
    lds[w * 2048 + row * 64 + rl]      = acc0[r];
    lds[w * 2048 + row * 64 + 32 + rl] = acc1[r];
  }
  __syncthreads();

  const int row  = tid >> 4;         // 0..31 token row
  const int colq = tid & 15;         // 16B expert chunk
  float l0 = 0.f, l1 = 0.f, l2 = 0.f, l3 = 0.f;
  for (int wv = 0; wv < 8; ++wv) {   // ascending: deterministic
    float4 v = *(const float4*)&lds[wv * 2048 + row * 64 + colq * 4];
    l0 += v.x; l1 += v.y; l2 += v.z; l3 += v.w;
  }
  l0 *= invT; l1 *= invT; l2 *= invT; l3 *= invT;

  float m = fmaxf(fmaxf(l0, l1), fmaxf(l2, l3));
#pragma unroll
  for (int d = 1; d < 16; d <<= 1) m = fmaxf(m, __shfl_xor(m, d));

  float ls0 = l0 - m, ls1 = l1 - m, ls2 = l2 - m, ls3 = l3 - m;
  float e0 = __expf(ls0), e1 = __expf(ls1), e2 = __expf(ls2), e3 = __expf(ls3);
  float ssum = e0 + e1 + e2 + e3;
  float dot  = e0 * ls0 + e1 * ls1 + e2 * ls2 + e3 * ls3;
#pragma unroll
  for (int d = 1; d < 16; d <<= 1) {
    ssum += __shfl_xor(ssum, d);
    dot  += __shfl_xor(dot, d);
  }
  const float inv_s = 1.0f / ssum;
  const float ent = __logf(ssum) - dot * inv_s;   // -sum p log p

  const int eb = colq * 4;
  float b1 = e0, b2 = -1.0f;
  int   i1 = eb, i2 = eb + 1;
  {
    float ev[3] = {e1, e2, e3};
#pragma unroll
    for (int j = 0; j < 3; ++j) {
      int ej = eb + 1 + j;
      if (better(ev[j], ej, b1, i1)) { b2 = b1; i2 = i1; b1 = ev[j]; i1 = ej; }
      else if (better(ev[j], ej, b2, i2)) { b2 = ev[j]; i2 = ej; }
    }
  }
#pragma unroll
  for (int d = 1; d < 16; d <<= 1) {
    float ob1 = __shfl_xor(b1, d), ob2 = __shfl_xor(b2, d);
    int   oi1 = __shfl_xor(i1, d), oi2 = __shfl_xor(i2, d);
    if (better(ob1, oi1, b1, i1)) {
      if (better(b1, i1, ob2, oi2)) { b2 = b1; i2 = i1; }
      else                          { b2 = ob2; i2 = oi2; }
      b1 = ob1; i1 = oi1;
    } else if (better(ob1, oi1, b2, i2)) {
      b2 = ob1; i2 = oi1;
    }
  }

  const int t = t0 + row;
  if (colq == 0) {
    out[OFF_PROBS + (size_t)t * 2 + 0] = b1 * inv_s;
    out[OFF_PROBS + (size_t)t * 2 + 1] = b2 * inv_s;
    out[OFF_IDX   + (size_t)t * 2 + 0] = (float)i1;
    out[OFF_IDX   + (size_t)t * 2 + 1] = (float)i2;
  }
  {
    float4 mv;
    mv.x = ((eb + 0 == i1) || (eb + 0 == i2)) ? 1.0f : 0.0f;
    mv.y = ((eb + 1 == i1) || (eb + 1 == i2)) ? 1.0f : 0.0f;
    mv.z = ((eb + 2 == i1) || (eb + 2 == i2)) ? 1.0f : 0.0f;
    mv.w = ((eb + 3 == i1) || (eb + 3 == i2)) ? 1.0f : 0.0f;
    *(float4*)&out[OFF_MASK + (size_t)t * N_EXP + eb] = mv;
  }

  // ---- block aux partials (deterministic fixed order) ----
  __syncthreads();
  {
    float4 p4;
    p4.x = e0 * inv_s; p4.y = e1 * inv_s; p4.z = e2 * inv_s; p4.w = e3 * inv_s;
    *(float4*)&lds[row * 64 + eb] = p4;
  }
  if (colq == 0) {
    lds[2048 + row] = (float)i1;
    lds[2080 + row] = (float)i2;
    lds[2112 + row] = ent;
  }
  __syncthreads();
  if (tid < 64) {
    float simp = 0.0f, sld = 0.0f;
    const float fe = (float)tid;
    for (int r = 0; r < 32; ++r) simp += lds[r * 64 + tid];
    for (int r = 0; r < 32; ++r)
      sld += ((lds[2048 + r] == fe) ? 1.0f : 0.0f)
           + ((lds[2080 + r] == fe) ? 1.0f : 0.0f);
    imp_part[blockIdx.x * N_EXP + tid]  = simp;
    load_part[blockIdx.x * N_EXP + tid] = sld;
    float v = (tid < 32) ? lds[2112 + tid] : 0.0f;
#pragma unroll
    for (int d = 1; d < 64; d <<= 1) v += __shfl_xor(v, d);
    if (tid == 0) ent_part[blockIdx.x] = v;
  }
}

// r20: MERGED finalize -- one dispatch instead of two. Phase 1 replicates
// finalize_part verbatim (64 blocks x 8 source blocks, same pairwise tree).
// Last-arriving block (ticket) replicates finalize_final verbatim. Unlike
// r14's disaster (512 blocks fencing MID-fused), fences here are 64 cheap
// post-fused threadfences + 1 atomic each; fused is untouched.
// Release: all threads fence before tid0's ticket atomic. Acquire: leader
// block fences (all threads) after winning, then reads imp2/load2/ent2.
__global__ __launch_bounds__(256) void finalize_kernel(
    const float* __restrict__ imp_part, const float* __restrict__ load_part,
    const float* __restrict__ ent_part, float* __restrict__ imp2,
    float* __restrict__ load2, float* __restrict__ ent2,
    u32* __restrict__ ticket, float* __restrict__ out) {
  __shared__ float si[4][64], sl[4][64], se[4];
  __shared__ float bc;
  const int tid  = threadIdx.x;
  const int lane = tid & 63;
  const int q    = tid >> 6;
  const int base = blockIdx.x * 8 + q * 2;     // 2 source blocks per quarter
  float a = imp_part[(size_t)base * N_EXP + lane]
          + imp_part[(size_t)(base + 1) * N_EXP + lane];
  float b = load_part[(size_t)base * N_EXP + lane]
          + load_part[(size_t)(base + 1) * N_EXP + lane];
  si[q][lane] = a;
  sl[q][lane] = b;
  if (lane == 0) se[q] = ent_part[base] + ent_part[base + 1];
  __syncthreads();
  if (tid < 64) {
    imp2[blockIdx.x * N_EXP + tid]  = si[0][tid] + si[1][tid] + si[2][tid] + si[3][tid];
    load2[blockIdx.x * N_EXP + tid] = sl[0][tid] + sl[1][tid] + sl[2][tid] + sl[3][tid];
    if (tid == 0) ent2[blockIdx.x] = se[0] + se[1] + se[2] + se[3];
  }
  __syncthreads();                       // level-1 stores done block-wide
  __threadfence();                       // release (all threads' stores)
  if (tid == 0) {
    u32 old = atomicAdd(ticket, 1u);
    bc = (float)old;
  }
  __syncthreads();
  if ((int)bc == 63) {                   // last block (block-uniform branch)
    __threadfence();                     // acquire: see other blocks' level-1
    // ---- finalize_final verbatim (reusing si/sl) ----
    float a2 = 0.0f, b2 = 0.0f;
    for (int r = q * 16; r < q * 16 + 16; ++r) {   // ascending: deterministic
      a2 += imp2[r * N_EXP + lane];
      b2 += load2[r * N_EXP + lane];
    }
    si[q][lane] = a2;
    sl[q][lane] = b2;
    __syncthreads();
    if (tid < 64) {
      float imp = si[0][tid] + si[1][tid] + si[2][tid] + si[3][tid];
      float ld  = sl[0][tid] + sl[1][tid] + sl[2][tid] + sl[3][tid];
      imp *= (1.0f / 16384.0f);
      ld  *= (1.0f / (16384.0f + 1e-6f));
      float prod = imp * ld;
      float e = ent2[tid];
#pragma unroll
      for (int d = 1; d < 64; d <<= 1) {
        prod += __shfl_xor(prod, d);
        e    += __shfl_xor(e, d);
      }
      if (tid == 0) {
        out[OFF_AUX] = prod * 64.0f * 0.01f;
        out[OFF_ENT] = (e / 16384.0f) * 0.01f;
      }
    }
  }
}

extern "C" void kernel_launch(void* const* d_in, const int* in_sizes, int n_in,
                              void* d_out, int out_size, void* d_ws, size_t ws_size,
                              hipStream_t stream) {
  const float* x    = (const float*)d_in[0];
  const float* W    = (const float*)d_in[1];
  const float* temp = (const float*)d_in[2];
  float* out = (float*)d_out;
  float* ws  = (float*)d_ws;

  // ws floats: Wf 196608 | imp 32768 | load 32768 | ent 512 | imp2 4096 |
  //            load2 4096 | ent2 64 | ticket (1 u32)
  bf16x8* Wf    = (bf16x8*)ws;
  float*  imp   = ws + 196608;
  float*  ldp   = imp + NBLK * N_EXP;
  float*  entp  = ldp + NBLK * N_EXP;
  float*  imp2  = entp + NBLK;
  float*  load2 = imp2 + 64 * N_EXP;
  float*  ent2  = load2 + 64 * N_EXP;
  u32*    tick  = (u32*)(ent2 + 64);

  wprep_kernel<<<64, 256, 0, stream>>>(W, Wf, tick);
  fused_kernel<<<NBLK, 512, 0, stream>>>(x, Wf, temp, out, imp, ldp, entp);
  finalize_kernel<<<64, 256, 0, stream>>>(imp, ldp, entp, imp2, load2, ent2,
                                          tick, out);
}

// Round 12
// 44.832 us; speedup vs baseline: 1.0812x; 1.0812x over previous
//
#include <hip/hip_runtime.h>
#include <hip/hip_bf16.h>
#include <math.h>

#define D_MODEL 2048
#define N_EXP   64
#define NTOK    16384           // 4 * 4096
#define NBLK    512             // NTOK / 32 tokens per block
#define NSTG    16              // K stages: 2048 / 128

typedef short bf16x8 __attribute__((ext_vector_type(8)));
typedef float f32x16 __attribute__((ext_vector_type(16)));
typedef unsigned int u32;

// out layout (floats)
#define OFF_PROBS 0
#define OFF_IDX   32768
#define OFF_MASK  65536
#define OFF_AUX   1114112
#define OFF_ENT   1114113

#define WF_PS 16384            // bf16x8 units per split-part (128 g * 2 n * 64)

#define MEMFENCE asm volatile("" ::: "memory")
// fence + barrier + fence: s_barrier alone is NOT a compiler memory fence;
// without the trailing fence the compiler may hoist next-stage LDS reads
// above the barrier (r9 failure: cross-wave stage rows read stale).
#define FULLBAR() do { MEMFENCE; __builtin_amdgcn_s_barrier(); MEMFENCE; \
                       __builtin_amdgcn_sched_barrier(0); } while (0)

__device__ __forceinline__ void split3(float xv, u32& h, u32& m, u32& l) {
  u32 xb = __builtin_bit_cast(u32, xv);
  u32 hb = xb & 0xFFFF0000u;
  float tf = xv - __builtin_bit_cast(float, hb);      // exact (Sterbenz)
  u32 tb = __builtin_bit_cast(u32, tf);
  u32 mb = tb & 0xFFFF0000u;
  float t2 = tf - __builtin_bit_cast(float, mb);      // exact; bf16-representable
  u32 lb = __builtin_bit_cast(u32, t2);
  h = hb >> 16; m = mb >> 16; l = lb >> 16;
}

__device__ __forceinline__ bool better(float a, int ia, float b, int ib) {
  return (a > b) || (a == b && ia < ib);
}

// W[64][2048] -> 3 bf16 parts in 32x32x16 B-fragment order. (verified r5-r8)
__global__ __launch_bounds__(256) void wprep_kernel(
    const float* __restrict__ W, bf16x8* __restrict__ Wf) {
  int gid  = blockIdx.x * 256 + threadIdx.x;   // 16384
  int g    = gid >> 7;
  int n    = (gid >> 6) & 1;
  int lane = gid & 63;
  int e    = n * 32 + (lane & 31);
  int k    = g * 16 + ((lane >> 5) << 3);
  const float* wr = W + (size_t)e * D_MODEL + k;
  bf16x8 hv, mv, lv;
#pragma unroll
  for (int j = 0; j < 8; ++j) {
    u32 h, m, l;
    split3(wr[j], h, m, l);
    hv[j] = (short)h; mv[j] = (short)m; lv[j] = (short)l;
  }
  Wf[gid]             = hv;
  Wf[WF_PS + gid]     = mv;
  Wf[2 * WF_PS + gid] = lv;
}

// r21: REVERT to the round-8 best-measured configuration byte-for-byte
// (44.40us): r17 fused (st0 = b & 15 K-phase stagger -- the channel-camping
// fix, the session's one big win) + split finalize.
// r20 post-mortem: merged ticket-finalize regressed (48.5) -- second
// confirmation (after r14) that cross-block fence reductions lose to a
// plain dispatch boundary. Session ledger: schedule variants all
// null/negative (r10/r11/r13/r15/r16/r18); stagger won and is saturated
// (r19 null); dispatch consolidation regressed twice (r14/r20). This is
// the verified optimum configuration.
__global__ __launch_bounds__(512, 4) void fused_kernel(
    const float* __restrict__ x, const bf16x8* __restrict__ Wf,
    const float* __restrict__ temp, float* __restrict__ out,
    float* __restrict__ imp_part, float* __restrict__ load_part,
    float* __restrict__ ent_part) {
  __shared__ float lds[16384];   // 64 KB: 4 bufs x 32 rows x 128 floats
  const int tid  = threadIdx.x;
  const int w    = tid >> 6;
  const int lane = tid & 63;
  const int t0   = blockIdx.x * 32;
  const int rl   = lane & 31;
  const int hg   = lane >> 5;
  const int st0  = blockIdx.x & 15;      // K-phase stagger (r17, verified)

  float tv = temp[0];
  tv = fminf(fmaxf(tv, 0.1f), 5.0f);
  const float invT = 1.0f / tv;

  // glds source bases (i=0,1): rows r0=w*4+i*2; lane covers row r0+hg,
  // physical chunk (lane&31) holds logical chunk (lane&31)^row.
  const float* gsrc[2];
#pragma unroll
  for (int i = 0; i < 2; ++i) {
    int r0  = w * 4 + i * 2;
    int row = r0 + hg;
    int sc  = rl ^ (row & 31);
    gsrc[i] = x + (size_t)(t0 + row) * D_MODEL + sc * 4;
  }

  auto stage = [&](int st) {             // st = physical stage index
    const int buf = st & 3;
    const int kst = (st0 + st) & 15;     // logical k-stage
#pragma unroll
    for (int i = 0; i < 2; ++i) {
      int r0 = w * 4 + i * 2;             // wave-uniform dest base
      __builtin_amdgcn_global_load_lds(
          (const __attribute__((address_space(1))) void*)(gsrc[i] + kst * 128),
          (__attribute__((address_space(3))) void*)(lds + buf * 4096 + r0 * 128),
          16, 0, 0);
    }
  };
  auto loadB = [&](int st, bf16x8* bb) { // st = physical stage index
    const int kst = (st0 + st) & 15;
    const bf16x8* wp = Wf + (size_t)(kst * 8 + w) * 128 + lane;
#pragma unroll
    for (int p = 0; p < 3; ++p)
#pragma unroll
      for (int n = 0; n < 2; ++n)
        bb[p * 2 + n] = wp[p * WF_PS + n * 64];
  };

  f32x16 acc0, acc1;
#pragma unroll
  for (int i = 0; i < 16; ++i) { acc0[i] = 0.0f; acc1[i] = 0.0f; }

  bf16x8 b[2][6];
  stage(0); stage(1);            // 4 glds in flight
  loadB(0, b[0]);                // 6 B-loads
  // S0 retired when newer-than-S0 (S1:2 + B0:6 = 8) are the only outstanding
  asm volatile("s_waitcnt vmcnt(8)" ::: "memory");
  FULLBAR();

  const int c0 = w * 4 + hg * 2;         // logical 16B-chunk of this lane

#pragma unroll
  for (int st = 0; st < NSTG; ++st) {
    if (st + 1 < NSTG) loadB(st + 1, b[(st + 1) & 1]);
    if (st + 2 < NSTG) stage(st + 2);

    const float* rb = lds + (st & 3) * 4096 + rl * 128;
    float4 a0 = *(const float4*)(rb + ((c0 ^ rl) << 2));
    float4 a1 = *(const float4*)(rb + (((c0 + 1) ^ rl) << 2));
    float av[8] = {a0.x, a0.y, a0.z, a0.w, a1.x, a1.y, a1.z, a1.w};
    bf16x8 ah, am, al;
#pragma unroll
    for (int j = 0; j < 8; ++j) {
      u32 hh, mm, ll;
      split3(av[j], hh, mm, ll);
      ah[j] = (short)hh; am[j] = (short)mm; al[j] = (short)ll;
    }
    const bf16x8* bb = b[st & 1];
    acc0 = __builtin_amdgcn_mfma_f32_32x32x16_bf16(ah, bb[0], acc0, 0, 0, 0);
    acc1 = __builtin_amdgcn_mfma_f32_32x32x16_bf16(ah, bb[1], acc1, 0, 0, 0);
    acc0 = __builtin_amdgcn_mfma_f32_32x32x16_bf16(ah, bb[2], acc0, 0, 0, 0);
    acc1 = __builtin_amdgcn_mfma_f32_32x32x16_bf16(ah, bb[3], acc1, 0, 0, 0);
    acc0 = __builtin_amdgcn_mfma_f32_32x32x16_bf16(am, bb[0], acc0, 0, 0, 0);
    acc1 = __builtin_amdgcn_mfma_f32_32x32x16_bf16(am, bb[1], acc1, 0, 0, 0);
    acc0 = __builtin_amdgcn_mfma_f32_32x32x16_bf16(am, bb[2], acc0, 0, 0, 0);
    acc1 = __builtin_amdgcn_mfma_f32_32x32x16_bf16(am, bb[3], acc1, 0, 0, 0);
    acc0 = __builtin_amdgcn_mfma_f32_32x32x16_bf16(ah, bb[4], acc0, 0, 0, 0);
    acc1 = __builtin_amdgcn_mfma_f32_32x32x16_bf16(ah, bb[5], acc1, 0, 0, 0);
    acc0 = __builtin_amdgcn_mfma_f32_32x32x16_bf16(al, bb[0], acc0, 0, 0, 0);
    acc1 = __builtin_amdgcn_mfma_f32_32x32x16_bf16(al, bb[1], acc1, 0, 0, 0);

    // end-of-stage: S(st+1) retired iff newest 8 (B(st+1):6 + S(st+2):2)
    // are the only outstanding. Tail st=14: only B15:6 newer -> vmcnt(6).
    if (st < NSTG - 2) {
      asm volatile("s_waitcnt vmcnt(8)" ::: "memory");
      FULLBAR();
    } else if (st == NSTG - 2) {
      asm volatile("s_waitcnt vmcnt(6)" ::: "memory");
      FULLBAR();
    }
  }

  // ---- epilogue: 8-way K reduction in LDS (verified r7/r8) ----
  __syncthreads();
#pragma unroll
  for (int r = 0; r < 16; ++r) {
    int row = (r & 3) + ((r >> 2) << 3) + (hg << 2);
    lds[w * 2048 + row * 64 + rl]      = acc0[r];
    lds[w * 2048 + row * 64 + 32 + rl] = acc1[r];
  }
  __syncthreads();

  const int row  = tid >> 4;         // 0..31 token row
  const int colq = tid & 15;         // 16B expert chunk
  float l0 = 0.f, l1 = 0.f, l2 = 0.f, l3 = 0.f;
  for (int wv = 0; wv < 8; ++wv) {   // ascending: deterministic
    float4 v = *(const float4*)&lds[wv * 2048 + row * 64 + colq * 4];
    l0 += v.x; l1 += v.y; l2 += v.z; l3 += v.w;
  }
  l0 *= invT; l1 *= invT; l2 *= invT; l3 *= invT;

  float m = fmaxf(fmaxf(l0, l1), fmaxf(l2, l3));
#pragma unroll
  for (int d = 1; d < 16; d <<= 1) m = fmaxf(m, __shfl_xor(m, d));

  float ls0 = l0 - m, ls1 = l1 - m, ls2 = l2 - m, ls3 = l3 - m;
  float e0 = __expf(ls0), e1 = __expf(ls1), e2 = __expf(ls2), e3 = __expf(ls3);
  float ssum = e0 + e1 + e2 + e3;
  float dot  = e0 * ls0 + e1 * ls1 + e2 * ls2 + e3 * ls3;
#pragma unroll
  for (int d = 1; d < 16; d <<= 1) {
    ssum += __shfl_xor(ssum, d);
    dot  += __shfl_xor(dot, d);
  }
  const float inv_s = 1.0f / ssum;
  const float ent = __logf(ssum) - dot * inv_s;   // -sum p log p

  const int eb = colq * 4;
  float b1 = e0, b2 = -1.0f;
  int   i1 = eb, i2 = eb + 1;
  {
    float ev[3] = {e1, e2, e3};
#pragma unroll
    for (int j = 0; j < 3; ++j) {
      int ej = eb + 1 + j;
      if (better(ev[j], ej, b1, i1)) { b2 = b1; i2 = i1; b1 = ev[j]; i1 = ej; }
      else if (better(ev[j], ej, b2, i2)) { b2 = ev[j]; i2 = ej; }
    }
  }
#pragma unroll
  for (int d = 1; d < 16; d <<= 1) {
    float ob1 = __shfl_xor(b1, d), ob2 = __shfl_xor(b2, d);
    int   oi1 = __shfl_xor(i1, d), oi2 = __shfl_xor(i2, d);
    if (better(ob1, oi1, b1, i1)) {
      if (better(b1, i1, ob2, oi2)) { b2 = b1; i2 = i1; }
      else                          { b2 = ob2; i2 = oi2; }
      b1 = ob1; i1 = oi1;
    } else if (better(ob1, oi1, b2, i2)) {
      b2 = ob1; i2 = oi1;
    }
  }

  const int t = t0 + row;
  if (colq == 0) {
    out[OFF_PROBS + (size_t)t * 2 + 0] = b1 * inv_s;
    out[OFF_PROBS + (size_t)t * 2 + 1] = b2 * inv_s;
    out[OFF_IDX   + (size_t)t * 2 + 0] = (float)i1;
    out[OFF_IDX   + (size_t)t * 2 + 1] = (float)i2;
  }
  {
    float4 mv;
    mv.x = ((eb + 0 == i1) || (eb + 0 == i2)) ? 1.0f : 0.0f;
    mv.y = ((eb + 1 == i1) || (eb + 1 == i2)) ? 1.0f : 0.0f;
    mv.z = ((eb + 2 == i1) || (eb + 2 == i2)) ? 1.0f : 0.0f;
    mv.w = ((eb + 3 == i1) || (eb + 3 == i2)) ? 1.0f : 0.0f;
    *(float4*)&out[OFF_MASK + (size_t)t * N_EXP + eb] = mv;
  }

  // ---- block aux partials (deterministic fixed order) ----
  __syncthreads();
  {
    float4 p4;
    p4.x = e0 * inv_s; p4.y = e1 * inv_s; p4.z = e2 * inv_s; p4.w = e3 * inv_s;
    *(float4*)&lds[row * 64 + eb] = p4;
  }
  if (colq == 0) {
    lds[2048 + row] = (float)i1;
    lds[2080 + row] = (float)i2;
    lds[2112 + row] = ent;
  }
  __syncthreads();
  if (tid < 64) {
    float simp = 0.0f, sld = 0.0f;
    const float fe = (float)tid;
    for (int r = 0; r < 32; ++r) simp += lds[r * 64 + tid];
    for (int r = 0; r < 32; ++r)
      sld += ((lds[2048 + r] == fe) ? 1.0f : 0.0f)
           + ((lds[2080 + r] == fe) ? 1.0f : 0.0f);
    imp_part[blockIdx.x * N_EXP + tid]  = simp;
    load_part[blockIdx.x * N_EXP + tid] = sld;
    float v = (tid < 32) ? lds[2112 + tid] : 0.0f;
#pragma unroll
    for (int d = 1; d < 64; d <<= 1) v += __shfl_xor(v, d);
    if (tid == 0) ent_part[blockIdx.x] = v;
  }
}

// Finalize split (validated r11/r12, absmax unchanged): parallel partial
// reduce (64 blocks) + single-block final. Fixed order -> deterministic.
__global__ __launch_bounds__(256) void finalize_part(
    const float* __restrict__ imp_part, const float* __restrict__ load_part,
    const float* __restrict__ ent_part, float* __restrict__ imp2,
    float* __restrict__ load2, float* __restrict__ ent2) {
  __shared__ float si[4][64], sl[4][64], se[4];
  const int tid  = threadIdx.x;
  const int lane = tid & 63;
  const int q    = tid >> 6;
  const int base = blockIdx.x * 8 + q * 2;     // 2 source blocks per quarter
  float a = imp_part[(size_t)base * N_EXP + lane]
          + imp_part[(size_t)(base + 1) * N_EXP + lane];
  float b = load_part[(size_t)base * N_EXP + lane]
          + load_part[(size_t)(base + 1) * N_EXP + lane];
  si[q][lane] = a;
  sl[q][lane] = b;
  if (lane == 0) se[q] = ent_part[base] + ent_part[base + 1];
  __syncthreads();
  if (tid < 64) {
    imp2[blockIdx.x * N_EXP + tid]  = si[0][tid] + si[1][tid] + si[2][tid] + si[3][tid];
    load2[blockIdx.x * N_EXP + tid] = sl[0][tid] + sl[1][tid] + sl[2][tid] + sl[3][tid];
    if (tid == 0) ent2[blockIdx.x] = se[0] + se[1] + se[2] + se[3];
  }
}

__global__ __launch_bounds__(256) void finalize_final(
    const float* __restrict__ imp2, const float* __restrict__ load2,
    const float* __restrict__ ent2, float* __restrict__ out) {
  __shared__ float si[4][64], sl[4][64];
  const int tid  = threadIdx.x;
  const int lane = tid & 63;
  const int q    = tid >> 6;
  float a = 0.0f, b = 0.0f;
  for (int r = q * 16; r < q * 16 + 16; ++r) {   // ascending: deterministic
    a += imp2[r * N_EXP + lane];
    b += load2[r * N_EXP + lane];
  }
  si[q][lane] = a;
  sl[q][lane] = b;
  __syncthreads();
  if (tid < 64) {
    float imp = si[0][tid] + si[1][tid] + si[2][tid] + si[3][tid];
    float ld  = sl[0][tid] + sl[1][tid] + sl[2][tid] + sl[3][tid];
    imp *= (1.0f / 16384.0f);
    ld  *= (1.0f / (16384.0f + 1e-6f));
    float prod = imp * ld;
    float e = ent2[tid];
#pragma unroll
    for (int d = 1; d < 64; d <<= 1) {
      prod += __shfl_xor(prod, d);
      e    += __shfl_xor(e, d);
    }
    if (tid == 0) {
      out[OFF_AUX] = prod * 64.0f * 0.01f;
      out[OFF_ENT] = (e / 16384.0f) * 0.01f;
    }
  }
}

extern "C" void kernel_launch(void* const* d_in, const int* in_sizes, int n_in,
                              void* d_out, int out_size, void* d_ws, size_t ws_size,
                              hipStream_t stream) {
  const float* x    = (const float*)d_in[0];
  const float* W    = (const float*)d_in[1];
  const float* temp = (const float*)d_in[2];
  float* out = (float*)d_out;
  float* ws  = (float*)d_ws;

  // ws floats: Wf 196608 | imp 32768 | load 32768 | ent 512 | imp2 4096 |
  //            load2 4096 | ent2 64
  bf16x8* Wf    = (bf16x8*)ws;
  float*  imp   = ws + 196608;
  float*  ldp   = imp + NBLK * N_EXP;
  float*  entp  = ldp + NBLK * N_EXP;
  float*  imp2  = entp + NBLK;
  float*  load2 = imp2 + 64 * N_EXP;
  float*  ent2  = load2 + 64 * N_EXP;

  wprep_kernel<<<64, 256, 0, stream>>>(W, Wf);
  fused_kernel<<<NBLK, 512, 0, stream>>>(x, Wf, temp, out, imp, ldp, entp);
  finalize_part<<<64, 256, 0, stream>>>(imp, ldp, entp, imp2, load2, ent2);
  finalize_final<<<1, 256, 0, stream>>>(imp2, load2, ent2, out);
}